// Round 10
// baseline (469.769 us; speedup 1.0000x reference)
//
#include <hip/hip_runtime.h>

#define T_TOKENS 8192
#define IN_F 4096
#define OUT_F 11008

#define BM 256
#define BN 256
#define NT (IN_F / 64)   // 64 K-tiles of 64 (two k32-slices each)

typedef __attribute__((ext_vector_type(4))) int v4i;
typedef __attribute__((ext_vector_type(16))) int v16i;

__device__ __forceinline__ void load_lds16(const signed char* g, const signed char* l) {
    __builtin_amdgcn_global_load_lds(
        (const __attribute__((address_space(1))) void*)g,
        (__attribute__((address_space(3))) void*)l, 16, 0, 0);
}

// Fragment-major layout for both operands:
//   buf[blk32][k32][lane][16B], lane = hi*32 + l31, holding
//   src[blk*32 + l31][k32*32 + hi*16 .. +16]   (16 int8)
// Byte-identical to the mfma_i32_32x32x32_i8 A/B fragment per lane.

// ------------- Pass 1: fused quant (frag-major xq) + weight repack -------------
__global__ __launch_bounds__(256) void quant_repack_kernel(
        const float* __restrict__ x, signed char* __restrict__ xq,
        float* __restrict__ qscale, const int* __restrict__ w32,
        signed char* __restrict__ w8) {
    if (blockIdx.x < T_TOKENS) {
        const int row = blockIdx.x;
        const int t = threadIdx.x;
        const float4* xr = (const float4*)(x + (size_t)row * IN_F) + t * 4;
        float4 v[4];
        float am = 0.f;
#pragma unroll
        for (int i = 0; i < 4; ++i) {
            v[i] = xr[i];
            am = fmaxf(am, fmaxf(fmaxf(fabsf(v[i].x), fabsf(v[i].y)),
                                 fmaxf(fabsf(v[i].z), fabsf(v[i].w))));
        }
#pragma unroll
        for (int off = 32; off > 0; off >>= 1)
            am = fmaxf(am, __shfl_xor(am, off, 64));
        __shared__ float wmax[4];
        const int wv = t >> 6;
        if ((t & 63) == 0) wmax[wv] = am;
        __syncthreads();
        float amax = fmaxf(fmaxf(wmax[0], wmax[1]), fmaxf(wmax[2], wmax[3]));
        float qs = amax * (1.0f / 127.0f);
        if (qs < 1e-30f) qs = 1e-30f;
        const float inv = 1.0f / qs;
        if (t == 0) qscale[row] = qs;
        int q[16];
#pragma unroll
        for (int i = 0; i < 4; ++i) {
            q[i * 4 + 0] = max(-128, min(127, (int)rintf(v[i].x * inv)));
            q[i * 4 + 1] = max(-128, min(127, (int)rintf(v[i].y * inv)));
            q[i * 4 + 2] = max(-128, min(127, (int)rintf(v[i].z * inv)));
            q[i * 4 + 3] = max(-128, min(127, (int)rintf(v[i].w * inv)));
        }
        v4i p;
#pragma unroll
        for (int i = 0; i < 4; ++i)
            p[i] = (q[i * 4] & 255) | ((q[i * 4 + 1] & 255) << 8) |
                   ((q[i * 4 + 2] & 255) << 16) | ((q[i * 4 + 3] & 255) << 24);
        const int k32 = t >> 1, hi = t & 1;
        *(v4i*)(xq + (((size_t)(row >> 5)) * 128 + k32) * 1024 +
                ((hi * 32) + (row & 31)) * 16) = p;
    } else {
        const int bb = blockIdx.x - T_TOKENS;
        const int nblk = bb >> 5;
        const int kg = bb & 31;
        const int t = threadIdx.x;
        __shared__ signed char tile[32][144];
        const int rrow = t >> 3, c8 = t & 7;
        const int* src = w32 + (size_t)(nblk * 32 + rrow) * IN_F + kg * 128 + c8 * 16;
        v4i pk;
#pragma unroll
        for (int j = 0; j < 4; ++j) {
            v4i w = ((const v4i*)src)[j];
            pk[j] = (w[0] & 255) | ((w[1] & 255) << 8) |
                    ((w[2] & 255) << 16) | ((w[3] & 255) << 24);
        }
        *(v4i*)&tile[rrow][c8 * 16] = pk;
        __syncthreads();
        const int k32l = t >> 6, lane = t & 63;
        const int hi = lane >> 5, l31 = lane & 31;
        v4i o = *(const v4i*)&tile[l31][k32l * 32 + hi * 16];
        *(v4i*)(w8 + ((size_t)(nblk)*128 + kg * 4 + k32l) * 1024 + lane * 16) = o;
    }
}

// ------------- Pass 2: int8 GEMM, 8 waves x (128x64), ring-5, 1 barrier ------
// Block 256x256, 8 waves (2M x 4N), per-wave 128x64 via acc[4][2] (128 AGPR)
// -> ~206 regs -> 2 waves/SIMD (TLP hides wave-serial LDS/issue under MFMA).
// LDS: ring of 5 x 32KB frag-major bufs (conflict-free b128, linear gload).
// Phase p: vmcnt(12) lgkmcnt(0) -> barrier -> stage tile p+4 (4 gload/wave,
// AFTER barrier: every wave's reads of the target buf drained pre-barrier)
// -> ds_read 12 frags of tile p -> setprio(1) 16 MFMA setprio(0).
__global__ __launch_bounds__(512, 2) void gemm_kernel(
        const signed char* __restrict__ A, const signed char* __restrict__ B,
        const float* __restrict__ qscale, const float* __restrict__ bias,
        const float* __restrict__ dqs, float* __restrict__ out) {
    __shared__ __align__(16) signed char smem_[5 * 32768];  // 160 KB
    signed char* smem = smem_;

    const int tid = threadIdx.x;
    const int wid = tid >> 6;   // 0..7
    const int lane = tid & 63;
    const int wm = wid >> 2;    // 0..1
    const int wn = wid & 3;     // 0..3
    const int l31 = lane & 31;
    const int hi = lane >> 5;

    // XCD map: XCD k owns m-tiles [4k,4k+4), sweeps n. Bijective (1376 = 8*172).
    const int b = (int)blockIdx.x;
    const int xcd = b & 7;
    const int idx = b >> 3;
    const int m0 = (xcd * 4 + (idx & 3)) * BM;
    const int n0 = (idx >> 2) * BN;

    // staging: wave w stages A mblk w (2 x 1KB) + B nblk w (2 x 1KB) per tile
    const signed char* aS[2];
    const signed char* bS[2];
    int ldsA[2], ldsB[2];
#pragma unroll
    for (int c = 0; c < 2; ++c) {
        aS[c] = A + ((size_t)((m0 >> 5) + wid)) * 131072 + c * 1024 + lane * 16;
        bS[c] = B + ((size_t)((n0 >> 5) + wid)) * 131072 + c * 1024 + lane * 16;
        ldsA[c] = wid * 2048 + c * 1024;            // wave-uniform; HW adds lane*16
        ldsB[c] = 16384 + wid * 2048 + c * 1024;
    }
    // fragment read offsets (contiguous per wave -> conflict-free)
    int rdA[4][2], rdB[2][2];
#pragma unroll
    for (int im = 0; im < 4; ++im)
#pragma unroll
        for (int ks = 0; ks < 2; ++ks)
            rdA[im][ks] = (wm * 4 + im) * 2048 + ks * 1024 + lane * 16;
#pragma unroll
    for (int in = 0; in < 2; ++in)
#pragma unroll
        for (int ks = 0; ks < 2; ++ks)
            rdB[in][ks] = 16384 + (wn * 2 + in) * 2048 + ks * 1024 + lane * 16;

    v16i acc[4][2] = {};

    // ---- prologue: stage tiles 0..3 into bufs 0..3 (16 gloads/wave) ----
#pragma unroll
    for (int tt = 0; tt < 4; ++tt)
#pragma unroll
        for (int c = 0; c < 2; ++c) {
            load_lds16(aS[c] + tt * 2048, smem + tt * 32768 + ldsA[c]);
            load_lds16(bS[c] + tt * 2048, smem + tt * 32768 + ldsB[c]);
        }

    // PH: BUF=compute buf, SBUF=stage buf, KT=staged tile, VMC=vmcnt, DOSTAGE
#define PH(BUF, SBUF, KT, VMC, DOSTAGE) do {                                   \
    asm volatile("s_waitcnt vmcnt(" #VMC ") lgkmcnt(0)" ::: "memory");         \
    __builtin_amdgcn_sched_barrier(0);                                         \
    __builtin_amdgcn_s_barrier();                                              \
    __builtin_amdgcn_sched_barrier(0);                                         \
    if (DOSTAGE) {                                                             \
        const int ko_ = (KT) * 2048;                                           \
        _Pragma("unroll")                                                      \
        for (int c = 0; c < 2; ++c) {                                          \
            load_lds16(aS[c] + ko_, smem + (SBUF) * 32768 + ldsA[c]);          \
            load_lds16(bS[c] + ko_, smem + (SBUF) * 32768 + ldsB[c]);          \
        }                                                                      \
    }                                                                          \
    __builtin_amdgcn_sched_barrier(0);                                         \
    {                                                                          \
        const signed char* rb_ = smem + (BUF) * 32768;                         \
        v4i a_[4][2], bf_[2][2];                                               \
        _Pragma("unroll")                                                      \
        for (int im = 0; im < 4; ++im)                                         \
            _Pragma("unroll")                                                  \
            for (int ks = 0; ks < 2; ++ks)                                     \
                a_[im][ks] = *(const v4i*)(rb_ + rdA[im][ks]);                 \
        _Pragma("unroll")                                                      \
        for (int in = 0; in < 2; ++in)                                         \
            _Pragma("unroll")                                                  \
            for (int ks = 0; ks < 2; ++ks)                                     \
                bf_[in][ks] = *(const v4i*)(rb_ + rdB[in][ks]);                \
        __builtin_amdgcn_s_setprio(1);                                         \
        _Pragma("unroll")                                                      \
        for (int ks = 0; ks < 2; ++ks)                                         \
            _Pragma("unroll")                                                  \
            for (int im = 0; im < 4; ++im)                                     \
                _Pragma("unroll")                                              \
                for (int in = 0; in < 2; ++in)                                 \
                    acc[im][in] = __builtin_amdgcn_mfma_i32_32x32x32_i8(       \
                        a_[im][ks], bf_[in][ks], acc[im][in], 0, 0, 0);        \
        __builtin_amdgcn_s_setprio(0);                                         \
    }                                                                          \
} while (0)

    // main: 12 x 5 phases (tiles 0..59), buf indices static mod 5
    for (int p = 0; p < 60; p += 5) {
        PH(0, 4, p + 4, 12, 1);
        PH(1, 0, p + 5, 12, 1);
        PH(2, 1, p + 6, 12, 1);
        PH(3, 2, p + 7, 12, 1);
        PH(4, 3, p + 8, 12, 1);
    }
    // tail: tiles 60..63 (no staging; drain 12 -> 8 -> 4 -> 0)
    PH(0, 0, 0, 12, 0);
    PH(1, 0, 0, 8,  0);
    PH(2, 0, 0, 4,  0);
    PH(3, 0, 0, 0,  0);
#undef PH

    // ---- epilogue: dequant + bias ----
    const float dq = dqs[0];
#pragma unroll
    for (int im = 0; im < 4; ++im) {
        float qsv[16];
#pragma unroll
        for (int r = 0; r < 16; ++r) {
            const int trow = wm * 128 + im * 32 + (r & 3) + 8 * (r >> 2) + 4 * hi;
            qsv[r] = dq * qscale[m0 + trow];
        }
#pragma unroll
        for (int in = 0; in < 2; ++in) {
            const int col = n0 + wn * 64 + in * 32 + l31;
            const float bv = bias[col];
#pragma unroll
            for (int r = 0; r < 16; ++r) {
                const int trow = wm * 128 + im * 32 + (r & 3) + 8 * (r >> 2) + 4 * hi;
                out[(size_t)(m0 + trow) * OUT_F + col] =
                    qsv[r] * (float)acc[im][in][r] + bv;
            }
        }
    }
}

extern "C" void kernel_launch(void* const* d_in, const int* in_sizes, int n_in,
                              void* d_out, int out_size, void* d_ws, size_t ws_size,
                              hipStream_t stream) {
    const float* x    = (const float*)d_in[0];
    const int*   w32  = (const int*)d_in[1];   // int8 values stored as int32
    const float* bias = (const float*)d_in[2];
    const float* dqs  = (const float*)d_in[3];
    float* out = (float*)d_out;

    signed char* xq = (signed char*)d_ws;                                   // 33.55 MB
    float* qscale   = (float*)((char*)d_ws + (size_t)T_TOKENS * IN_F);      // 32 KB
    signed char* w8 = (signed char*)((char*)d_ws + (size_t)T_TOKENS * IN_F
                                     + (size_t)T_TOKENS * 4);               // 45.1 MB

    quant_repack_kernel<<<T_TOKENS + (OUT_F / 32) * 32, 256, 0, stream>>>(
        x, xq, qscale, w32, w8);
    dim3 g((T_TOKENS / BM) * (OUT_F / BN));  // 1376
    gemm_kernel<<<g, 512, 0, stream>>>(xq, w8, qscale, bias, dqs, out);
}

// Round 11
// 466.683 us; speedup vs baseline: 1.0066x; 1.0066x over previous
//
#include <hip/hip_runtime.h>

#define T_TOKENS 8192
#define IN_F 4096
#define OUT_F 11008

#define BM 256
#define BN 256
#define NT (IN_F / 64)   // 64 K-tiles of 64 (two k32-slices each)

typedef __attribute__((ext_vector_type(4))) int v4i;
typedef __attribute__((ext_vector_type(16))) int v16i;

__device__ __forceinline__ void load_lds16(const signed char* g, const signed char* l) {
    __builtin_amdgcn_global_load_lds(
        (const __attribute__((address_space(1))) void*)g,
        (__attribute__((address_space(3))) void*)l, 16, 0, 0);
}

// Fragment-major layout for both operands:
//   buf[blk32][k32][lane][16B], lane = hi*32 + l31, holding
//   src[blk*32 + l31][k32*32 + hi*16 .. +16]   (16 int8)
// Byte-identical to the mfma_i32_32x32x32_i8 A/B fragment per lane.

// ------------- Pass 1: fused quant (frag-major xq) + weight repack -------------
__global__ __launch_bounds__(256) void quant_repack_kernel(
        const float* __restrict__ x, signed char* __restrict__ xq,
        float* __restrict__ qscale, const int* __restrict__ w32,
        signed char* __restrict__ w8) {
    if (blockIdx.x < T_TOKENS) {
        const int row = blockIdx.x;
        const int t = threadIdx.x;
        const float4* xr = (const float4*)(x + (size_t)row * IN_F) + t * 4;
        float4 v[4];
        float am = 0.f;
#pragma unroll
        for (int i = 0; i < 4; ++i) {
            v[i] = xr[i];
            am = fmaxf(am, fmaxf(fmaxf(fabsf(v[i].x), fabsf(v[i].y)),
                                 fmaxf(fabsf(v[i].z), fabsf(v[i].w))));
        }
#pragma unroll
        for (int off = 32; off > 0; off >>= 1)
            am = fmaxf(am, __shfl_xor(am, off, 64));
        __shared__ float wmax[4];
        const int wv = t >> 6;
        if ((t & 63) == 0) wmax[wv] = am;
        __syncthreads();
        float amax = fmaxf(fmaxf(wmax[0], wmax[1]), fmaxf(wmax[2], wmax[3]));
        float qs = amax * (1.0f / 127.0f);
        if (qs < 1e-30f) qs = 1e-30f;
        const float inv = 1.0f / qs;
        if (t == 0) qscale[row] = qs;
        int q[16];
#pragma unroll
        for (int i = 0; i < 4; ++i) {
            q[i * 4 + 0] = max(-128, min(127, (int)rintf(v[i].x * inv)));
            q[i * 4 + 1] = max(-128, min(127, (int)rintf(v[i].y * inv)));
            q[i * 4 + 2] = max(-128, min(127, (int)rintf(v[i].z * inv)));
            q[i * 4 + 3] = max(-128, min(127, (int)rintf(v[i].w * inv)));
        }
        v4i p;
#pragma unroll
        for (int i = 0; i < 4; ++i)
            p[i] = (q[i * 4] & 255) | ((q[i * 4 + 1] & 255) << 8) |
                   ((q[i * 4 + 2] & 255) << 16) | ((q[i * 4 + 3] & 255) << 24);
        const int k32 = t >> 1, hi = t & 1;
        *(v4i*)(xq + (((size_t)(row >> 5)) * 128 + k32) * 1024 +
                ((hi * 32) + (row & 31)) * 16) = p;
    } else {
        const int bb = blockIdx.x - T_TOKENS;
        const int nblk = bb >> 5;
        const int kg = bb & 31;
        const int t = threadIdx.x;
        __shared__ signed char tile[32][144];
        const int rrow = t >> 3, c8 = t & 7;
        const int* src = w32 + (size_t)(nblk * 32 + rrow) * IN_F + kg * 128 + c8 * 16;
        v4i pk;
#pragma unroll
        for (int j = 0; j < 4; ++j) {
            v4i w = ((const v4i*)src)[j];
            pk[j] = (w[0] & 255) | ((w[1] & 255) << 8) |
                    ((w[2] & 255) << 16) | ((w[3] & 255) << 24);
        }
        *(v4i*)&tile[rrow][c8 * 16] = pk;
        __syncthreads();
        const int k32l = t >> 6, lane = t & 63;
        const int hi = lane >> 5, l31 = lane & 31;
        v4i o = *(const v4i*)&tile[l31][k32l * 32 + hi * 16];
        *(v4i*)(w8 + ((size_t)(nblk)*128 + kg * 4 + k32l) * 1024 + lane * 16) = o;
    }
}

// ------------- Pass 2: int8 GEMM, 8 waves x (128x64), ring-5, m201 2-phase ---
// Block 256x256, 8 waves (2M x 4N), per-wave 128x64 via acc[4][2] (128 AGPR)
// + ~128 VGPR -> 2 waves/SIMD. LDS: ring-5 x 32KB frag-major bufs.
// m201-style fine phases, sized for i8's thin MFMA mass: each K-tile = 2
// sub-phases of {barrier -> stage 2 gloads (tile t+4) -> ds_reads ->
// lgkmcnt(0)+sched_barrier -> setprio(1) 8 MFMA setprio(0)}.
// vmcnt(12) counted once per tile (never 0 until tail drain 8/4/0).
__global__ __launch_bounds__(512, 2) void gemm_kernel(
        const signed char* __restrict__ A, const signed char* __restrict__ B,
        const float* __restrict__ qscale, const float* __restrict__ bias,
        const float* __restrict__ dqs, float* __restrict__ out) {
    __shared__ __align__(16) signed char smem_[5 * 32768];  // 160 KB
    signed char* smem = smem_;

    const int tid = threadIdx.x;
    const int wid = tid >> 6;   // 0..7
    const int lane = tid & 63;
    const int wm = wid >> 2;    // 0..1
    const int wn = wid & 3;     // 0..3
    const int l31 = lane & 31;
    const int hi = lane >> 5;

    // XCD map: XCD k owns m-tiles [4k,4k+4), sweeps n. Bijective (1376 = 8*172).
    const int b = (int)blockIdx.x;
    const int xcd = b & 7;
    const int idx = b >> 3;
    const int m0 = (xcd * 4 + (idx & 3)) * BM;
    const int n0 = (idx >> 2) * BN;

    // staging: wave w stages A mblk w (2 x 1KB) + B nblk w (2 x 1KB) per tile
    const signed char* aS[2];
    const signed char* bS[2];
    int ldsA[2], ldsB[2];
#pragma unroll
    for (int c = 0; c < 2; ++c) {
        aS[c] = A + ((size_t)((m0 >> 5) + wid)) * 131072 + c * 1024 + lane * 16;
        bS[c] = B + ((size_t)((n0 >> 5) + wid)) * 131072 + c * 1024 + lane * 16;
        ldsA[c] = wid * 2048 + c * 1024;            // wave-uniform; HW adds lane*16
        ldsB[c] = 16384 + wid * 2048 + c * 1024;
    }
    // fragment read offsets (contiguous per wave -> conflict-free)
    int rdA[4][2], rdB[2][2];
#pragma unroll
    for (int im = 0; im < 4; ++im)
#pragma unroll
        for (int ks = 0; ks < 2; ++ks)
            rdA[im][ks] = (wm * 4 + im) * 2048 + ks * 1024 + lane * 16;
#pragma unroll
    for (int in = 0; in < 2; ++in)
#pragma unroll
        for (int ks = 0; ks < 2; ++ks)
            rdB[in][ks] = 16384 + (wn * 2 + in) * 2048 + ks * 1024 + lane * 16;

    v16i acc[4][2] = {};

    // ---- prologue: stage tiles 0..3 into bufs 0..3 (16 gloads/wave) ----
#pragma unroll
    for (int tt = 0; tt < 4; ++tt)
#pragma unroll
        for (int c = 0; c < 2; ++c) {
            load_lds16(aS[c] + tt * 2048, smem + tt * 32768 + ldsA[c]);
            load_lds16(bS[c] + tt * 2048, smem + tt * 32768 + ldsB[c]);
        }

    // TILE(BUF, SBUF, KT, VMC, DOSTAGE): one K-tile as two m201-style phases.
#define TILE(BUF, SBUF, KT, VMC, DOSTAGE) do {                                 \
    /* --- sub-phase 0: a01 + b reads; stage A-chunks; MFMA im=0,1 --- */      \
    asm volatile("s_waitcnt vmcnt(" #VMC ") lgkmcnt(0)" ::: "memory");         \
    __builtin_amdgcn_sched_barrier(0);                                         \
    __builtin_amdgcn_s_barrier();                                              \
    __builtin_amdgcn_sched_barrier(0);                                         \
    if (DOSTAGE) {                                                             \
        load_lds16(aS[0] + (KT) * 2048, smem + (SBUF) * 32768 + ldsA[0]);      \
        load_lds16(aS[1] + (KT) * 2048, smem + (SBUF) * 32768 + ldsA[1]);      \
    }                                                                          \
    __builtin_amdgcn_sched_barrier(0);                                         \
    {                                                                          \
        const signed char* rb_ = smem + (BUF) * 32768;                         \
        v4i a_[4][2], bf_[2][2];                                               \
        _Pragma("unroll")                                                      \
        for (int im = 0; im < 2; ++im)                                         \
            _Pragma("unroll")                                                  \
            for (int ks = 0; ks < 2; ++ks)                                     \
                a_[im][ks] = *(const v4i*)(rb_ + rdA[im][ks]);                 \
        _Pragma("unroll")                                                      \
        for (int in = 0; in < 2; ++in)                                         \
            _Pragma("unroll")                                                  \
            for (int ks = 0; ks < 2; ++ks)                                     \
                bf_[in][ks] = *(const v4i*)(rb_ + rdB[in][ks]);                \
        asm volatile("s_waitcnt lgkmcnt(0)" ::: "memory");                     \
        __builtin_amdgcn_sched_barrier(0);                                     \
        __builtin_amdgcn_s_setprio(1);                                         \
        _Pragma("unroll")                                                      \
        for (int ks = 0; ks < 2; ++ks)                                         \
            _Pragma("unroll")                                                  \
            for (int im = 0; im < 2; ++im)                                     \
                _Pragma("unroll")                                              \
                for (int in = 0; in < 2; ++in)                                 \
                    acc[im][in] = __builtin_amdgcn_mfma_i32_32x32x32_i8(       \
                        a_[im][ks], bf_[in][ks], acc[im][in], 0, 0, 0);        \
        __builtin_amdgcn_s_setprio(0);                                         \
        __builtin_amdgcn_sched_barrier(0);                                     \
        /* --- sub-phase 1: a23 reads; stage B-chunks; MFMA im=2,3 --- */      \
        __builtin_amdgcn_s_barrier();                                          \
        __builtin_amdgcn_sched_barrier(0);                                     \
        if (DOSTAGE) {                                                         \
            load_lds16(bS[0] + (KT) * 2048, smem + (SBUF) * 32768 + ldsB[0]);  \
            load_lds16(bS[1] + (KT) * 2048, smem + (SBUF) * 32768 + ldsB[1]);  \
        }                                                                      \
        __builtin_amdgcn_sched_barrier(0);                                     \
        _Pragma("unroll")                                                      \
        for (int im = 0; im < 2; ++im)                                         \
            _Pragma("unroll")                                                  \
            for (int ks = 0; ks < 2; ++ks)                                     \
                a_[2 + im][ks] = *(const v4i*)(rb_ + rdA[2 + im][ks]);         \
        asm volatile("s_waitcnt lgkmcnt(0)" ::: "memory");                     \
        __builtin_amdgcn_sched_barrier(0);                                     \
        __builtin_amdgcn_s_setprio(1);                                         \
        _Pragma("unroll")                                                      \
        for (int ks = 0; ks < 2; ++ks)                                         \
            _Pragma("unroll")                                                  \
            for (int im = 0; im < 2; ++im)                                     \
                _Pragma("unroll")                                              \
                for (int in = 0; in < 2; ++in)                                 \
                    acc[2 + im][in] = __builtin_amdgcn_mfma_i32_32x32x32_i8(   \
                        a_[2 + im][ks], bf_[in][ks], acc[2 + im][in], 0, 0, 0);\
        __builtin_amdgcn_s_setprio(0);                                         \
    }                                                                          \
} while (0)

    // main: 12 x 5 tiles (0..59), buf indices static mod 5
    for (int p = 0; p < 60; p += 5) {
        TILE(0, 4, p + 4, 12, 1);
        TILE(1, 0, p + 5, 12, 1);
        TILE(2, 1, p + 6, 12, 1);
        TILE(3, 2, p + 7, 12, 1);
        TILE(4, 3, p + 8, 12, 1);
    }
    // tail: tiles 60..63 (no staging; drain 12 -> 8 -> 4 -> 0)
    TILE(0, 0, 0, 12, 0);
    TILE(1, 0, 0, 8,  0);
    TILE(2, 0, 0, 4,  0);
    TILE(3, 0, 0, 0,  0);
#undef TILE

    // ---- epilogue: dequant + bias ----
    const float dq = dqs[0];
#pragma unroll
    for (int im = 0; im < 4; ++im) {
        float qsv[16];
#pragma unroll
        for (int r = 0; r < 16; ++r) {
            const int trow = wm * 128 + im * 32 + (r & 3) + 8 * (r >> 2) + 4 * hi;
            qsv[r] = dq * qscale[m0 + trow];
        }
#pragma unroll
        for (int in = 0; in < 2; ++in) {
            const int col = n0 + wn * 64 + in * 32 + l31;
            const float bv = bias[col];
#pragma unroll
            for (int r = 0; r < 16; ++r) {
                const int trow = wm * 128 + im * 32 + (r & 3) + 8 * (r >> 2) + 4 * hi;
                out[(size_t)(m0 + trow) * OUT_F + col] =
                    qsv[r] * (float)acc[im][in][r] + bv;
            }
        }
    }
}

extern "C" void kernel_launch(void* const* d_in, const int* in_sizes, int n_in,
                              void* d_out, int out_size, void* d_ws, size_t ws_size,
                              hipStream_t stream) {
    const float* x    = (const float*)d_in[0];
    const int*   w32  = (const int*)d_in[1];   // int8 values stored as int32
    const float* bias = (const float*)d_in[2];
    const float* dqs  = (const float*)d_in[3];
    float* out = (float*)d_out;

    signed char* xq = (signed char*)d_ws;                                   // 33.55 MB
    float* qscale   = (float*)((char*)d_ws + (size_t)T_TOKENS * IN_F);      // 32 KB
    signed char* w8 = (signed char*)((char*)d_ws + (size_t)T_TOKENS * IN_F
                                     + (size_t)T_TOKENS * 4);               // 45.1 MB

    quant_repack_kernel<<<T_TOKENS + (OUT_F / 32) * 32, 256, 0, stream>>>(
        x, xq, qscale, w32, w8);
    dim3 g((T_TOKENS / BM) * (OUT_F / BN));  // 1376
    gemm_kernel<<<g, 512, 0, stream>>>(xq, w8, qscale, bias, dqs, out);
}